// Round 14
// baseline (186.574 us; speedup 1.0000x reference)
//
#include <hip/hip_runtime.h>
#include <stdint.h>

// DecisionTree: out = sum_l p_l * (x @ W_l^T + b_l), p from bottom-layer sigmoids.
// Pair-folded + A-prescaled: ONE flat GEMM A[4096x9216] @ B[1024x9216]^T.
// r14: tree_gemm11 = champion gemm8 schedule, but A is reg-staged from a SINGLE
// 8MB bf16 x-copy and scaled by p in-register during staging (cvt_pk_bf16_f32),
// eliminating the 72MB xs materialization (prep 30us -> ~19us). B path, waits,
// barriers, MFMA schedule byte-identical to the proven r13 champion.

#define M_TOK 4096
#define DDIM  1024
#define KFLAT 9216

typedef __bf16 bf16x8 __attribute__((ext_vector_type(8)));
typedef float  f32x4  __attribute__((ext_vector_type(4)));
typedef unsigned short u16x4 __attribute__((ext_vector_type(4)));
typedef unsigned short u16x8 __attribute__((ext_vector_type(8)));

#define GLB(p) ((const __attribute__((address_space(1))) void*)(p))
#define LDS(p) ((__attribute__((address_space(3))) void*)(p))

__device__ __forceinline__ unsigned short f2bf(float f) {
    union { float f; uint32_t u; } v; v.f = f;
    uint32_t u = v.u;
    return (unsigned short)((u + 0x7fffu + ((u >> 16) & 1u)) >> 16);  // RNE
}

__device__ __forceinline__ bf16x8 asbf(f32x4 v) {
    bf16x8 r; __builtin_memcpy(&r, &v, 16); return r;
}

template<int OFF>
__device__ __forceinline__ f32x4 dsr(uint32_t a) {
    f32x4 r;
    asm volatile("ds_read_b128 %0, %1 offset:%c2" : "=v"(r) : "v"(a), "i"(OFF));
    return r;
}

// ---- fused prep: blocks [0,1024) build W'(flat-K) + bias; [1024,2048) dec ----
// mode=1: dec writes xb = bf16(x) single copy [4096][1024]     (gemm11)
// mode=0: dec writes xs = 9 p-scaled copies [4096][9216]        (gemm8/3 fallback)
__global__ __launch_bounds__(256) void prep_dec_kernel(
    const float* __restrict__ x, const float* __restrict__ dec_w,
    const float* __restrict__ dec_b, const float* __restrict__ lw,
    const float* __restrict__ lb, unsigned short* __restrict__ wp,
    float* __restrict__ bw, unsigned short* __restrict__ xs,
    float* __restrict__ pmat, int mode)
{
    if (blockIdx.x < 1024) {
        int idx = blockIdx.x * 256 + threadIdx.x;     // (o, k4)
        int o  = idx >> 8;
        int k4 = (idx & 255) << 2;
        size_t src = (size_t)o * DDIM + k4;
        size_t dstb = (size_t)o * KFLAT + k4;
        float4 acc = make_float4(0.f, 0.f, 0.f, 0.f);
#pragma unroll
        for (int j = 0; j < 8; ++j) {
            const float4 a = *(const float4*)(lw + (size_t)(2*j)   * DDIM*DDIM + src);
            const float4 b = *(const float4*)(lw + (size_t)(2*j+1) * DDIM*DDIM + src);
            u16x4 d;
            d[0] = f2bf(a.x - b.x); d[1] = f2bf(a.y - b.y);
            d[2] = f2bf(a.z - b.z); d[3] = f2bf(a.w - b.w);
            *(u16x4*)(wp + dstb + (size_t)j * DDIM) = d;
            acc.x += b.x; acc.y += b.y; acc.z += b.z; acc.w += b.w;
        }
        u16x4 s;
        s[0] = f2bf(acc.x); s[1] = f2bf(acc.y); s[2] = f2bf(acc.z); s[3] = f2bf(acc.w);
        *(u16x4*)(wp + dstb + (size_t)8 * DDIM) = s;
        if ((idx & 255) == 0) {
            float sb = 0.f;
#pragma unroll
            for (int j = 0; j < 8; ++j) {
                float ba = lb[(2*j) * DDIM + o];
                float bb = lb[(2*j+1) * DDIM + o];
                bw[j * DDIM + o] = ba - bb;
                sb += bb;
            }
            bw[8 * DDIM + o] = sb;
        }
    } else {
        int m    = (blockIdx.x - 1024) * 4 + (threadIdx.x >> 6);
        int lane = threadIdx.x & 63;
        const float* xr = x + (size_t)m * DDIM + lane * 16;
        float xv[16];
        *(float4*)&xv[0]  = *(const float4*)(xr + 0);
        *(float4*)&xv[4]  = *(const float4*)(xr + 4);
        *(float4*)&xv[8]  = *(const float4*)(xr + 8);
        *(float4*)&xv[12] = *(const float4*)(xr + 12);
        float s[8];
#pragma unroll
        for (int j = 0; j < 8; ++j) {
            const float* wr = dec_w + (size_t)(7 + j) * DDIM + lane * 16;
            float a = 0.f;
#pragma unroll
            for (int i = 0; i < 16; i += 4) {
                float4 wv = *(const float4*)(wr + i);
                a = fmaf(xv[i], wv.x, fmaf(xv[i+1], wv.y, fmaf(xv[i+2], wv.z, fmaf(xv[i+3], wv.w, a))));
            }
            s[j] = a;
        }
#pragma unroll
        for (int j = 0; j < 8; ++j)
#pragma unroll
            for (int off = 32; off > 0; off >>= 1)
                s[j] += __shfl_xor(s[j], off);
        float p[8];
#pragma unroll
        for (int j = 0; j < 8; ++j)
            p[j] = 1.0f / (1.0f + expf(-(s[j] + dec_b[7 + j])));
        if (lane == 0) {
#pragma unroll
            for (int j = 0; j < 8; ++j)
                pmat[(size_t)m * 8 + j] = p[j];
        }
        if (mode) {
            // single bf16 copy
            unsigned short* dst = xs + (size_t)m * DDIM + lane * 16;
#pragma unroll
            for (int c = 0; c < 2; ++c) {
                u16x8 o;
#pragma unroll
                for (int e = 0; e < 8; ++e) o[e] = f2bf(xv[c * 8 + e]);
                *(u16x8*)(dst + c * 8) = o;
            }
        } else {
#pragma unroll
            for (int j = 0; j < 9; ++j) {
                float pj = (j < 8) ? p[j] : 1.0f;
                unsigned short* dst = xs + (size_t)m * KFLAT + j * DDIM + lane * 16;
#pragma unroll
                for (int c = 0; c < 2; ++c) {
                    u16x8 o;
#pragma unroll
                    for (int e = 0; e < 8; ++e) o[e] = f2bf(pj * xv[c * 8 + e]);
                    *(u16x8*)(dst + c * 8) = o;
                }
            }
        }
    }
}

// ---- wait macros ----
#define WAITV0 asm volatile("s_waitcnt vmcnt(0)" ::: "memory")
#define WAITV4 asm volatile("s_waitcnt vmcnt(4)" ::: "memory")
#define BARR   __builtin_amdgcn_s_barrier()
#define SBAR   __builtin_amdgcn_sched_barrier(0)
#define LGKM0  do { asm volatile("s_waitcnt lgkmcnt(0)" ::: "memory"); SBAR; } while(0)
#define LGKM4  do { asm volatile("s_waitcnt lgkmcnt(4)" ::: "memory"); SBAR; } while(0)

#define MFMA_Q(q, ASET, BSET) do { \
    __builtin_amdgcn_s_setprio(1); \
    _Pragma("unroll") \
    for (int mfl = 0; mfl < 2; ++mfl) { \
        _Pragma("unroll") \
        for (int j = 0; j < 4; ++j) { \
            acc[2*(q)+mfl][j] = __builtin_amdgcn_mfma_f32_16x16x32_bf16(asbf(ASET[mfl][0]), asbf(BSET[j][0]), acc[2*(q)+mfl][j], 0, 0, 0); \
            acc[2*(q)+mfl][j] = __builtin_amdgcn_mfma_f32_16x16x32_bf16(asbf(ASET[mfl][1]), asbf(BSET[j][1]), acc[2*(q)+mfl][j], 0, 0, 0); \
        } \
    } \
    __builtin_amdgcn_s_setprio(0); \
} while(0)

#define READ_A(SET, q, a0, a1) do { \
    SET[0][0] = dsr<(2*(q)+0)*2048>(a0); \
    SET[0][1] = dsr<(2*(q)+0)*2048>(a1); \
    SET[1][0] = dsr<(2*(q)+1)*2048>(a0); \
    SET[1][1] = dsr<(2*(q)+1)*2048>(a1); \
} while(0)

#define READ_B(SET, b0, b1) do { \
    SET[0][0] = dsr<0*2048>(b0); SET[0][1] = dsr<0*2048>(b1); \
    SET[1][0] = dsr<1*2048>(b0); SET[1][1] = dsr<1*2048>(b1); \
    SET[2][0] = dsr<2*2048>(b0); SET[2][1] = dsr<2*2048>(b1); \
    SET[3][0] = dsr<3*2048>(b0); SET[3][1] = dsr<3*2048>(b1); \
} while(0)

// scale 16B of bf16 (as f32x4 raw) by pc, repack -> f32x4 bit-image of 8 bf16
#define SCALE16(dstv, srcv, pc) do { \
    _Pragma("unroll") \
    for (int e = 0; e < 4; ++e) { \
        uint32_t u_ = __float_as_uint(srcv[e]); \
        float lo_ = __uint_as_float(u_ << 16) * (pc); \
        float hi_ = __uint_as_float(u_ & 0xffff0000u) * (pc); \
        uint32_t rr_; \
        asm volatile("v_cvt_pk_bf16_f32 %0, %1, %2" : "=v"(rr_) : "v"(lo_), "v"(hi_)); \
        dstv[e] = __uint_as_float(rr_); \
    } \
} while(0)

// ========== tree_gemm11: gemm8 schedule + reg-staged p-scaled A from 8MB xb ==========
// LDS: A0@0 A1@32K | B0@64K B1@96K B2@128K (160KB). Row=128B, G4 swizzle.
__global__ __launch_bounds__(512, 2) void tree_gemm11(
    const unsigned short* __restrict__ xb,   // [4096][1024] bf16 (UNSCALED)
    const unsigned short* __restrict__ wp,   // [1024][9216] bf16
    const float* __restrict__ pmat,          // [4096][8]
    float* __restrict__ out, float* __restrict__ parts, int KG)
{
    extern __shared__ char smem[];
    const int tid  = threadIdx.x;
    const int lane = tid & 63;
    const int w    = tid >> 6;
    const int wm   = w >> 2, wn = w & 3;     // 2M x 4N, wave tile 128x64
    const int ra   = lane & 15;
    const int g16  = lane >> 4;

    const int bx  = blockIdx.x;
    const int xcd = bx & 7, ii = bx >> 3;
    const int nt  = xcd >> 1;
    const int mt  = (xcd & 1) * 8 + ii;
    const int m0  = mt * 256, n0 = nt * 256;
    const int g   = blockIdx.y;
    const int k0  = g * KG;
    const int NT  = KG >> 6;                 // 36 (ks=4) or 48 (ks=3), even

    uint32_t sbase = (uint32_t)(uintptr_t)(__attribute__((address_space(3))) char*)smem;
    const uint32_t colb0 = (uint32_t)((g16 ^ (ra & 7)) << 4);
    const uint32_t colb1 = colb0 ^ 64;
    const uint32_t baseA0s = sbase + wm * 16384 + ra * 128 + colb0;
    const uint32_t baseA1s = sbase + wm * 16384 + ra * 128 + colb1;
    const uint32_t baseB0s = sbase + 65536 + wn * 8192 + ra * 128 + colb0;
    const uint32_t baseB1s = sbase + 65536 + wn * 8192 + ra * 128 + colb1;

    const int kel = (((lane & 7) ^ (lane >> 3)) & 7) * 8;   // inverse-G4 source chunk
    const int r0  = w * 8 + (lane >> 3);                    // thread's base row (0..63)
    const uint32_t wbs = sbase + (uint32_t)r0 * 128 + ((uint32_t)(lane & 7) << 4);

    auto stageB = [&](int buf, int tt, int hh) {
        const unsigned short* s0 = wp + (size_t)(n0 + hh * 128 + r0) * KFLAT + (k0 + tt * 64 + kel);
        char* d0 = smem + 65536 + buf * 32768 + hh * 16384 + w * 1024;
        __builtin_amdgcn_global_load_lds(GLB(s0), LDS(d0), 16, 0, 0);
        __builtin_amdgcn_global_load_lds(GLB(s0 + (size_t)64 * KFLAT), LDS(d0 + 8192), 16, 0, 0);
    };

    f32x4 acc[8][4] = {};
    f32x4 avA[2][2], avB[2][2], bvX[4][2], bvY[4][2];
    f32x4 araw[4];

    // ---- p preloads (3 leaves this block can touch) ----
    const int fl = k0 >> 10;
    float pv1[4], pv2[4], pcur[4];
#pragma unroll
    for (int i = 0; i < 4; ++i) {
        const float* pr = pmat + (size_t)(m0 + r0 + i * 64) * 8;
        pcur[i] = pr[fl];
        pv1[i]  = pr[fl + 1];
        pv2[i]  = (fl + 2 < 8) ? pr[fl + 2] : 1.0f;
    }
    // ---- A(0) raw loads (before stageB: FIFO order matters) ----
    {
        const int colw = k0 & 1023;
#pragma unroll
        for (int i = 0; i < 4; ++i)
            araw[i] = *(const f32x4*)(xb + (size_t)(m0 + r0 + i * 64) * DDIM + colw + kel);
    }
    SBAR;
    stageB(0, 0, 0); stageB(0, 0, 1);
    stageB(1, 1, 0); stageB(1, 1, 1);
    WAITV4;                                  // drains p, araw, stageB(0); leaves stageB(1)
#pragma unroll
    for (int i = 0; i < 4; ++i) {            // scale+write A(0) -> buf 0
        f32x4 sc;
        SCALE16(sc, araw[i], pcur[i]);
        asm volatile("ds_write_b128 %0, %1" :: "v"(wbs + i * 8192), "v"(sc) : "memory");
    }
    LGKM0;
    BARR;
    READ_B(bvX, baseB0s, baseB1s);
    READ_A(avA, 0, baseA0s, baseA1s);

    int bt1 = 1, bt2 = 2;                    // (t+1)%3, (t+2)%3

#define TILE_BODY11(T, CUR, NXT) do { \
    const int t_ = (T); \
    const bool s1 = (t_ + 1 < NT), s2 = (t_ + 2 < NT); \
    if (s1) { \
        const int colw_ = (k0 + (t_ + 1) * 64) & 1023; \
        _Pragma("unroll") \
        for (int i = 0; i < 4; ++i) \
            araw[i] = *(const f32x4*)(xb + (size_t)(m0 + r0 + i * 64) * DDIM + colw_ + kel); \
    } \
    SBAR; \
    if (s2) { stageB(bt2, t_ + 2, 0); stageB(bt2, t_ + 2, 1); } \
    const uint32_t a0_ = baseA0s + ((uint32_t)(t_ & 1) << 15); \
    const uint32_t a1_ = baseA1s + ((uint32_t)(t_ & 1) << 15); \
    READ_A(avB, 1, a0_, a1_); \
    LGKM4;  MFMA_Q(0, avA, CUR); \
    READ_A(avA, 2, a0_, a1_); \
    LGKM4;  MFMA_Q(1, avB, CUR); \
    READ_A(avB, 3, a0_, a1_); \
    LGKM4;  MFMA_Q(2, avA, CUR); \
    if (s1) { \
        if (s2) { WAITV4; } else { WAITV0; } \
        const int kk1_ = k0 + (t_ + 1) * 64; \
        if ((kk1_ & 1023) == 0) { \
            const bool l1_ = ((kk1_ >> 10) - fl) == 1; \
            _Pragma("unroll") \
            for (int i = 0; i < 4; ++i) pcur[i] = l1_ ? pv1[i] : pv2[i]; \
        } \
        const uint32_t wb_ = wbs + ((uint32_t)((t_ + 1) & 1) << 15); \
        _Pragma("unroll") \
        for (int i = 0; i < 4; ++i) { \
            f32x4 sc_; \
            SCALE16(sc_, araw[i], pcur[i]); \
            asm volatile("ds_write_b128 %0, %1" :: "v"(wb_ + i * 8192), "v"(sc_) : "memory"); \
        } \
    } \
    LGKM0; \
    if (s1) { \
        BARR; \
        const uint32_t nb0_ = baseB0s + (uint32_t)bt1 * 32768u; \
        const uint32_t nb1_ = baseB1s + (uint32_t)bt1 * 32768u; \
        const uint32_t na0_ = baseA0s + ((uint32_t)((t_ + 1) & 1) << 15); \
        const uint32_t na1_ = baseA1s + ((uint32_t)((t_ + 1) & 1) << 15); \
        READ_B(NXT, nb0_, nb1_); \
        READ_A(avA, 0, na0_, na1_); \
    } \
    MFMA_Q(3, avB, CUR); \
    SBAR; \
    bt1 = (bt1 == 2) ? 0 : bt1 + 1; \
    bt2 = (bt2 == 2) ? 0 : bt2 + 1; \
} while(0)

    for (int tp = 0; tp < NT; tp += 2) {
        TILE_BODY11(tp,     bvX, bvY);
        TILE_BODY11(tp + 1, bvY, bvX);
    }
#undef TILE_BODY11

    float* dst = (g == 0) ? out : parts + (size_t)(g - 1) * M_TOK * DDIM;
#pragma unroll
    for (int mf = 0; mf < 8; ++mf)
#pragma unroll
        for (int e = 0; e < 4; ++e) {
            int row = m0 + wm * 128 + mf * 16 + g16 * 4 + e;
#pragma unroll
            for (int j = 0; j < 4; ++j)
                dst[(size_t)row * DDIM + n0 + wn * 64 + j * 16 + ra] = acc[mf][j][e];
        }
}

// ---------------- reduce2: out = out + sum parts + bias(p . bw), grid-stride x2 ----------------
__global__ __launch_bounds__(256) void reduce2_kernel(
    float* __restrict__ out, const float* __restrict__ parts,
    const float* __restrict__ pmat, const float* __restrict__ bw, int np)
{
#pragma unroll
    for (int rep = 0; rep < 2; ++rep) {
        size_t i = (size_t)blockIdx.x * 512 + rep * 256 + threadIdx.x;
        int m   = (int)(i >> 8);
        int col = (int)(i & 255) * 4;
        float4 a = ((const float4*)out)[i];
        for (int p = 0; p < np; ++p) {
            float4 b = ((const float4*)(parts + (size_t)p * M_TOK * DDIM))[i];
            a.x += b.x; a.y += b.y; a.z += b.z; a.w += b.w;
        }
        float4 pa = *(const float4*)(pmat + (size_t)m * 8);
        float4 pb = *(const float4*)(pmat + (size_t)m * 8 + 4);
        float4 bias = *(const float4*)(bw + 8 * DDIM + col);
#pragma unroll
        for (int l = 0; l < 8; ++l) {
            float pl = (l < 4) ? ((const float*)&pa)[l] : ((const float*)&pb)[l - 4];
            float4 bl = *(const float4*)(bw + l * DDIM + col);
            bias.x = fmaf(pl, bl.x, bias.x); bias.y = fmaf(pl, bl.y, bias.y);
            bias.z = fmaf(pl, bl.z, bias.z); bias.w = fmaf(pl, bl.w, bias.w);
        }
        a.x += bias.x; a.y += bias.y; a.z += bias.z; a.w += bias.w;
        ((float4*)out)[i] = a;
    }
}

// ================= fallback (r13 champion): tree_gemm8 (needs xs 9-copy) =================
__global__ __launch_bounds__(512, 2) void tree_gemm8(
    const unsigned short* __restrict__ xs, const unsigned short* __restrict__ wp,
    float* __restrict__ out, float* __restrict__ parts, int KG)
{
    extern __shared__ char smem[];
    const int tid  = threadIdx.x;
    const int lane = tid & 63;
    const int w    = tid >> 6;
    const int wm   = w >> 2, wn = w & 3;
    const int ra   = lane & 15;
    const int g16  = lane >> 4;

    const int bx  = blockIdx.x;
    const int xcd = bx & 7, ii = bx >> 3;
    const int nt  = xcd >> 1;
    const int mt  = (xcd & 1) * 8 + ii;
    const int m0  = mt * 256, n0 = nt * 256;
    const int g   = blockIdx.y;
    const int k0  = g * KG;
    const int NT  = KG >> 6;

    uint32_t sbase = (uint32_t)(uintptr_t)(__attribute__((address_space(3))) char*)smem;
    const uint32_t colb0 = (uint32_t)((g16 ^ (ra & 7)) << 4);
    const uint32_t colb1 = colb0 ^ 64;
    const uint32_t baseA0s = sbase + wm * 16384 + ra * 128 + colb0;
    const uint32_t baseA1s = sbase + wm * 16384 + ra * 128 + colb1;
    const uint32_t baseB0s = sbase + 65536 + wn * 8192 + ra * 128 + colb0;
    const uint32_t baseB1s = sbase + 65536 + wn * 8192 + ra * 128 + colb1;

    const int kel = (((lane & 7) ^ (lane >> 3)) & 7) * 8;
    const int rA  = w * 8 + (lane >> 3);

    auto stageA = [&](int buf, int tt, int hh) {
        const unsigned short* s0 = xs + (size_t)(m0 + hh * 128 + rA) * KFLAT + (k0 + tt * 64 + kel);
        char* d0 = smem + buf * 32768 + hh * 16384 + w * 1024;
        __builtin_amdgcn_global_load_lds(GLB(s0), LDS(d0), 16, 0, 0);
        __builtin_amdgcn_global_load_lds(GLB(s0 + (size_t)64 * KFLAT), LDS(d0 + 8192), 16, 0, 0);
    };
    auto stageB = [&](int buf, int tt, int hh) {
        const unsigned short* s0 = wp + (size_t)(n0 + hh * 128 + rA) * KFLAT + (k0 + tt * 64 + kel);
        char* d0 = smem + 65536 + buf * 32768 + hh * 16384 + w * 1024;
        __builtin_amdgcn_global_load_lds(GLB(s0), LDS(d0), 16, 0, 0);
        __builtin_amdgcn_global_load_lds(GLB(s0 + (size_t)64 * KFLAT), LDS(d0 + 8192), 16, 0, 0);
    };

    f32x4 acc[8][4] = {};
    f32x4 avA[2][2], avB[2][2], bvX[4][2], bvY[4][2];

    stageA(0, 0, 0); stageA(0, 0, 1);
    stageB(0, 0, 0); stageB(0, 0, 1);
    stageB(1, 1, 0); stageB(1, 1, 1);
    WAITV4;
    BARR;
    READ_B(bvX, baseB0s, baseB1s);
    READ_A(avA, 0, baseA0s, baseA1s);

    int bt1 = 1, bt2 = 2;

#define TILE_BODY8(T, CUR, NXT) do { \
    const int t_ = (T); \
    const bool s1 = (t_ + 1 < NT), s2 = (t_ + 2 < NT); \
    if (s1) { stageA((t_ + 1) & 1, t_ + 1, 0); stageA((t_ + 1) & 1, t_ + 1, 1); } \
    if (s2) { stageB(bt2, t_ + 2, 0); stageB(bt2, t_ + 2, 1); } \
    const uint32_t a0_ = baseA0s + ((uint32_t)(t_ & 1) << 15); \
    const uint32_t a1_ = baseA1s + ((uint32_t)(t_ & 1) << 15); \
    READ_A(avB, 1, a0_, a1_); \
    LGKM4;  MFMA_Q(0, avA, CUR); \
    READ_A(avA, 2, a0_, a1_); \
    LGKM4;  MFMA_Q(1, avB, CUR); \
    READ_A(avB, 3, a0_, a1_); \
    LGKM4;  MFMA_Q(2, avA, CUR); \
    LGKM0; \
    if (s1) { \
        if (s2) { WAITV4; } else { WAITV0; } \
        BARR; \
        const uint32_t nb0_ = baseB0s + (uint32_t)bt1 * 32768u; \
        const uint32_t nb1_ = baseB1s + (uint32_t)bt1 * 32768u; \
        const uint32_t na0_ = baseA0s + ((uint32_t)((t_ + 1) & 1) << 15); \
        const uint32_t na1_ = baseA1s + ((uint32_t)((t_ + 1) & 1) << 15); \
        READ_B(NXT, nb0_, nb1_); \
        READ_A(avA, 0, na0_, na1_); \
    } \
    MFMA_Q(3, avB, CUR); \
    SBAR; \
    bt1 = (bt1 == 2) ? 0 : bt1 + 1; \
    bt2 = (bt2 == 2) ? 0 : bt2 + 1; \
} while(0)

    for (int tp = 0; tp < NT; tp += 2) {
        TILE_BODY8(tp,     bvX, bvY);
        TILE_BODY8(tp + 1, bvY, bvX);
    }
#undef TILE_BODY8

    float* dst = (g == 0) ? out : parts + (size_t)(g - 1) * M_TOK * DDIM;
#pragma unroll
    for (int mf = 0; mf < 8; ++mf)
#pragma unroll
        for (int e = 0; e < 4; ++e) {
            int row = m0 + wm * 128 + mf * 16 + g16 * 4 + e;
#pragma unroll
            for (int j = 0; j < 4; ++j)
                dst[(size_t)row * DDIM + n0 + wn * 64 + j * 16 + ra] = acc[mf][j][e];
        }
}

extern "C" void kernel_launch(void* const* d_in, const int* in_sizes, int n_in,
                              void* d_out, int out_size, void* d_ws, size_t ws_size,
                              hipStream_t stream) {
    (void)in_sizes; (void)n_in; (void)out_size;
    const float* x     = (const float*)d_in[0];
    const float* dec_w = (const float*)d_in[1];
    const float* dec_b = (const float*)d_in[2];
    const float* lw    = (const float*)d_in[3];
    const float* lb    = (const float*)d_in[4];
    float* out = (float*)d_out;
    uint8_t* w8 = (uint8_t*)d_ws;

    unsigned short* xs   = (unsigned short*)(w8);              // xb(8MB) or xs(72MB)
    unsigned short* wp   = (unsigned short*)(w8 + 75497472);
    float*          bw   = (float*)(w8 + 94371840);
    float*          pmat = (float*)(w8 + 94408704);
    float*          parts= (float*)(w8 + 94539776);
    const size_t NEED3 = 94539776 + 2ull * 16777216;
    const size_t NEED4 = 94539776 + 3ull * 16777216;

    int ks = (ws_size >= NEED4) ? 4 : (ws_size >= NEED3) ? 3 : 0;
    if (!ks) return;

    hipError_t e11 = hipFuncSetAttribute(
        reinterpret_cast<const void*>(tree_gemm11),
        hipFuncAttributeMaxDynamicSharedMemorySize, 163840);
    const bool use11 = (e11 == hipSuccess);

    prep_dec_kernel<<<2048, 256, 0, stream>>>(x, dec_w, dec_b, lw, lb, wp, bw, xs, pmat,
                                              use11 ? 1 : 0);

    if (use11) {
        tree_gemm11<<<dim3(64, ks), 512, 163840, stream>>>(xs, wp, pmat, out, parts, KFLAT / ks);
        reduce2_kernel<<<2048, 256, 0, stream>>>(out, parts, pmat, bw, ks - 1);
        return;
    }
    hipError_t e8 = hipFuncSetAttribute(
        reinterpret_cast<const void*>(tree_gemm8),
        hipFuncAttributeMaxDynamicSharedMemorySize, 163840);
    if (e8 == hipSuccess) {
        tree_gemm8<<<dim3(64, ks), 512, 163840, stream>>>(xs, wp, out, parts, KFLAT / ks);
        reduce2_kernel<<<2048, 256, 0, stream>>>(out, parts, pmat, bw, ks - 1);
    }
}

// Round 15
// 119.874 us; speedup vs baseline: 1.5564x; 1.5564x over previous
//
#include <hip/hip_runtime.h>
#include <stdint.h>

// DecisionTree: out = sum_l p_l * (x @ W_l^T + b_l), p from bottom-layer sigmoids.
// Pair-folded + A-prescaled: ONE flat GEMM A[4096x9216] @ B[1024x9216]^T.
// CHAMPION (r13, 119.9us): tree_gemm8 = 256^2 tile, BK=64, A 2-buf + B 3-buf LDS
// (160KB), G4 swizzle, flowing schedule with CROSS-TILE FRAGMENT PIPELINING.
// Dead ends (all regressed): B-direct-to-regs (r8/r11/r12/r14 - per-lane VMEM
// in K-loop loses to fire-and-forget global_load_lds DMA), 32x32 MFMA (r12),
// 2 blocks/CU (r9), reg-staged p-scaled A (r14).

#define M_TOK 4096
#define DDIM  1024
#define KFLAT 9216

typedef __bf16 bf16x8 __attribute__((ext_vector_type(8)));
typedef float  f32x4  __attribute__((ext_vector_type(4)));
typedef unsigned short u16x4 __attribute__((ext_vector_type(4)));
typedef unsigned short u16x8 __attribute__((ext_vector_type(8)));

#define GLB(p) ((const __attribute__((address_space(1))) void*)(p))
#define LDS(p) ((__attribute__((address_space(3))) void*)(p))

__device__ __forceinline__ unsigned short f2bf(float f) {
    union { float f; uint32_t u; } v; v.f = f;
    uint32_t u = v.u;
    return (unsigned short)((u + 0x7fffu + ((u >> 16) & 1u)) >> 16);  // RNE
}

__device__ __forceinline__ bf16x8 asbf(f32x4 v) {
    bf16x8 r; __builtin_memcpy(&r, &v, 16); return r;
}

template<int OFF>
__device__ __forceinline__ f32x4 dsr(uint32_t a) {
    f32x4 r;
    asm volatile("ds_read_b128 %0, %1 offset:%c2" : "=v"(r) : "v"(a), "i"(OFF));
    return r;
}

// ---- fused prep: blocks [0,1024) build W'(flat-K) + bias; [1024,2048) build xs + pmat ----
__global__ __launch_bounds__(256) void prep_dec_kernel(
    const float* __restrict__ x, const float* __restrict__ dec_w,
    const float* __restrict__ dec_b, const float* __restrict__ lw,
    const float* __restrict__ lb, unsigned short* __restrict__ wp,
    float* __restrict__ bw, unsigned short* __restrict__ xs,
    float* __restrict__ pmat)
{
    if (blockIdx.x < 1024) {
        int idx = blockIdx.x * 256 + threadIdx.x;     // (o, k4)
        int o  = idx >> 8;
        int k4 = (idx & 255) << 2;
        size_t src = (size_t)o * DDIM + k4;
        size_t dstb = (size_t)o * KFLAT + k4;
        float4 acc = make_float4(0.f, 0.f, 0.f, 0.f);
#pragma unroll
        for (int j = 0; j < 8; ++j) {
            const float4 a = *(const float4*)(lw + (size_t)(2*j)   * DDIM*DDIM + src);
            const float4 b = *(const float4*)(lw + (size_t)(2*j+1) * DDIM*DDIM + src);
            u16x4 d;
            d[0] = f2bf(a.x - b.x); d[1] = f2bf(a.y - b.y);
            d[2] = f2bf(a.z - b.z); d[3] = f2bf(a.w - b.w);
            *(u16x4*)(wp + dstb + (size_t)j * DDIM) = d;
            acc.x += b.x; acc.y += b.y; acc.z += b.z; acc.w += b.w;
        }
        u16x4 s;
        s[0] = f2bf(acc.x); s[1] = f2bf(acc.y); s[2] = f2bf(acc.z); s[3] = f2bf(acc.w);
        *(u16x4*)(wp + dstb + (size_t)8 * DDIM) = s;
        if ((idx & 255) == 0) {
            float sb = 0.f;
#pragma unroll
            for (int j = 0; j < 8; ++j) {
                float ba = lb[(2*j) * DDIM + o];
                float bb = lb[(2*j+1) * DDIM + o];
                bw[j * DDIM + o] = ba - bb;
                sb += bb;
            }
            bw[8 * DDIM + o] = sb;
        }
    } else {
        int m    = (blockIdx.x - 1024) * 4 + (threadIdx.x >> 6);
        int lane = threadIdx.x & 63;
        const float* xr = x + (size_t)m * DDIM + lane * 16;
        float xv[16];
        *(float4*)&xv[0]  = *(const float4*)(xr + 0);
        *(float4*)&xv[4]  = *(const float4*)(xr + 4);
        *(float4*)&xv[8]  = *(const float4*)(xr + 8);
        *(float4*)&xv[12] = *(const float4*)(xr + 12);
        float s[8];
#pragma unroll
        for (int j = 0; j < 8; ++j) {
            const float* wr = dec_w + (size_t)(7 + j) * DDIM + lane * 16;
            float a = 0.f;
#pragma unroll
            for (int i = 0; i < 16; i += 4) {
                float4 wv = *(const float4*)(wr + i);
                a = fmaf(xv[i], wv.x, fmaf(xv[i+1], wv.y, fmaf(xv[i+2], wv.z, fmaf(xv[i+3], wv.w, a))));
            }
            s[j] = a;
        }
#pragma unroll
        for (int j = 0; j < 8; ++j)
#pragma unroll
            for (int off = 32; off > 0; off >>= 1)
                s[j] += __shfl_xor(s[j], off);
        float p[8];
#pragma unroll
        for (int j = 0; j < 8; ++j)
            p[j] = 1.0f / (1.0f + expf(-(s[j] + dec_b[7 + j])));
        if (lane == 0) {
#pragma unroll
            for (int j = 0; j < 8; ++j)
                pmat[(size_t)m * 8 + j] = p[j];
        }
#pragma unroll
        for (int j = 0; j < 9; ++j) {
            float pj = (j < 8) ? p[j] : 1.0f;
            unsigned short* dst = xs + (size_t)m * KFLAT + j * DDIM + lane * 16;
#pragma unroll
            for (int c = 0; c < 2; ++c) {
                u16x8 o;
#pragma unroll
                for (int e = 0; e < 8; ++e) o[e] = f2bf(pj * xv[c * 8 + e]);
                *(u16x8*)(dst + c * 8) = o;
            }
        }
    }
}

// ---- wait macros ----
#define WAITV0 asm volatile("s_waitcnt vmcnt(0)" ::: "memory")
#define WAITV4 asm volatile("s_waitcnt vmcnt(4)" ::: "memory")
#define BARR   __builtin_amdgcn_s_barrier()
#define SBAR   __builtin_amdgcn_sched_barrier(0)
#define LGKM0  do { asm volatile("s_waitcnt lgkmcnt(0)" ::: "memory"); SBAR; } while(0)
#define LGKM4  do { asm volatile("s_waitcnt lgkmcnt(4)" ::: "memory"); SBAR; } while(0)

#define MFMA_Q(q, ASET, BSET) do { \
    __builtin_amdgcn_s_setprio(1); \
    _Pragma("unroll") \
    for (int mfl = 0; mfl < 2; ++mfl) { \
        _Pragma("unroll") \
        for (int j = 0; j < 4; ++j) { \
            acc[2*(q)+mfl][j] = __builtin_amdgcn_mfma_f32_16x16x32_bf16(asbf(ASET[mfl][0]), asbf(BSET[j][0]), acc[2*(q)+mfl][j], 0, 0, 0); \
            acc[2*(q)+mfl][j] = __builtin_amdgcn_mfma_f32_16x16x32_bf16(asbf(ASET[mfl][1]), asbf(BSET[j][1]), acc[2*(q)+mfl][j], 0, 0, 0); \
        } \
    } \
    __builtin_amdgcn_s_setprio(0); \
} while(0)

#define READ_A(SET, q, a0, a1) do { \
    SET[0][0] = dsr<(2*(q)+0)*2048>(a0); \
    SET[0][1] = dsr<(2*(q)+0)*2048>(a1); \
    SET[1][0] = dsr<(2*(q)+1)*2048>(a0); \
    SET[1][1] = dsr<(2*(q)+1)*2048>(a1); \
} while(0)

#define READ_B(SET, b0, b1) do { \
    SET[0][0] = dsr<0*2048>(b0); SET[0][1] = dsr<0*2048>(b1); \
    SET[1][0] = dsr<1*2048>(b0); SET[1][1] = dsr<1*2048>(b1); \
    SET[2][0] = dsr<2*2048>(b0); SET[2][1] = dsr<2*2048>(b1); \
    SET[3][0] = dsr<3*2048>(b0); SET[3][1] = dsr<3*2048>(b1); \
} while(0)

// ================= tree_gemm8 (champion): fragment-pipelined, 160 KB =================
// LDS: A0@0 A1@32K | B0@64K B1@96K B2@128K. Row = 128B, G4 swizzle byte^=(row&7)<<4.
// Per tile: body Q0-Q2 counted-lgkm; {LGKM0; vmcnt; BARR}; 12 next-tile ds_reads; Q3.
__global__ __launch_bounds__(512, 2) void tree_gemm8(
    const unsigned short* __restrict__ xs, const unsigned short* __restrict__ wp,
    float* __restrict__ out, float* __restrict__ parts, int KG)
{
    extern __shared__ char smem[];
    const int tid  = threadIdx.x;
    const int lane = tid & 63;
    const int w    = tid >> 6;
    const int wm   = w >> 2, wn = w & 3;     // 2M x 4N, wave tile 128x64
    const int ra   = lane & 15;
    const int g16  = lane >> 4;

    const int bx  = blockIdx.x;
    const int xcd = bx & 7, ii = bx >> 3;
    const int nt  = xcd >> 1;
    const int mt  = (xcd & 1) * 8 + ii;
    const int m0  = mt * 256, n0 = nt * 256;
    const int g   = blockIdx.y;
    const int k0  = g * KG;
    const int NT  = KG >> 6;                 // 36 (even)

    uint32_t sbase = (uint32_t)(uintptr_t)(__attribute__((address_space(3))) char*)smem;
    const uint32_t colb0 = (uint32_t)((g16 ^ (ra & 7)) << 4);
    const uint32_t colb1 = colb0 ^ 64;
    const uint32_t baseA0s = sbase + wm * 16384 + ra * 128 + colb0;
    const uint32_t baseA1s = sbase + wm * 16384 + ra * 128 + colb1;
    const uint32_t baseB0s = sbase + 65536 + wn * 8192 + ra * 128 + colb0;
    const uint32_t baseB1s = sbase + 65536 + wn * 8192 + ra * 128 + colb1;

    const int kel = (((lane & 7) ^ (lane >> 3)) & 7) * 8;
    const int rA  = w * 8 + (lane >> 3);

    auto stageA = [&](int buf, int tt, int hh) {
        const unsigned short* s0 = xs + (size_t)(m0 + hh * 128 + rA) * KFLAT + (k0 + tt * 64 + kel);
        char* d0 = smem + buf * 32768 + hh * 16384 + w * 1024;
        __builtin_amdgcn_global_load_lds(GLB(s0), LDS(d0), 16, 0, 0);
        __builtin_amdgcn_global_load_lds(GLB(s0 + (size_t)64 * KFLAT), LDS(d0 + 8192), 16, 0, 0);
    };
    auto stageB = [&](int buf, int tt, int hh) {
        const unsigned short* s0 = wp + (size_t)(n0 + hh * 128 + rA) * KFLAT + (k0 + tt * 64 + kel);
        char* d0 = smem + 65536 + buf * 32768 + hh * 16384 + w * 1024;
        __builtin_amdgcn_global_load_lds(GLB(s0), LDS(d0), 16, 0, 0);
        __builtin_amdgcn_global_load_lds(GLB(s0 + (size_t)64 * KFLAT), LDS(d0 + 8192), 16, 0, 0);
    };

    f32x4 acc[8][4] = {};
    f32x4 avA[2][2], avB[2][2], bvX[4][2], bvY[4][2];

    // prologue: A(0), B(0), B(1) = 12 gloads; vmcnt(4) drains tile-0, keeps B(1).
    stageA(0, 0, 0); stageA(0, 0, 1);
    stageB(0, 0, 0); stageB(0, 0, 1);
    stageB(1, 1, 0); stageB(1, 1, 1);
    WAITV4;
    BARR;
    READ_B(bvX, baseB0s, baseB1s);
    READ_A(avA, 0, baseA0s, baseA1s);

    int bt1 = 1, bt2 = 2;                    // (t+1)%3, (t+2)%3

#define TILE_BODY8(T, CUR, NXT) do { \
    const int t_ = (T); \
    const bool s1 = (t_ + 1 < NT), s2 = (t_ + 2 < NT); \
    if (s1) { stageA((t_ + 1) & 1, t_ + 1, 0); stageA((t_ + 1) & 1, t_ + 1, 1); } \
    if (s2) { stageB(bt2, t_ + 2, 0); stageB(bt2, t_ + 2, 1); } \
    const uint32_t a0_ = baseA0s + ((uint32_t)(t_ & 1) << 15); \
    const uint32_t a1_ = baseA1s + ((uint32_t)(t_ & 1) << 15); \
    READ_A(avB, 1, a0_, a1_); \
    LGKM4;  MFMA_Q(0, avA, CUR); \
    READ_A(avA, 2, a0_, a1_); \
    LGKM4;  MFMA_Q(1, avB, CUR); \
    READ_A(avB, 3, a0_, a1_); \
    LGKM4;  MFMA_Q(2, avA, CUR); \
    LGKM0; \
    if (s1) { \
        if (s2) { WAITV4; } else { WAITV0; } \
        BARR; \
        const uint32_t nb0_ = baseB0s + (uint32_t)bt1 * 32768u; \
        const uint32_t nb1_ = baseB1s + (uint32_t)bt1 * 32768u; \
        const uint32_t na0_ = baseA0s + ((uint32_t)((t_ + 1) & 1) << 15); \
        const uint32_t na1_ = baseA1s + ((uint32_t)((t_ + 1) & 1) << 15); \
        READ_B(NXT, nb0_, nb1_); \
        READ_A(avA, 0, na0_, na1_); \
    } \
    MFMA_Q(3, avB, CUR); \
    SBAR; \
    bt1 = (bt1 == 2) ? 0 : bt1 + 1; \
    bt2 = (bt2 == 2) ? 0 : bt2 + 1; \
} while(0)

    for (int tp = 0; tp < NT; tp += 2) {
        TILE_BODY8(tp,     bvX, bvY);
        TILE_BODY8(tp + 1, bvY, bvX);
    }
#undef TILE_BODY8

    float* dst = (g == 0) ? out : parts + (size_t)(g - 1) * M_TOK * DDIM;
#pragma unroll
    for (int mf = 0; mf < 8; ++mf)
#pragma unroll
        for (int e = 0; e < 4; ++e) {
            int row = m0 + wm * 128 + mf * 16 + g16 * 4 + e;
#pragma unroll
            for (int j = 0; j < 4; ++j)
                dst[(size_t)row * DDIM + n0 + wn * 64 + j * 16 + ra] = acc[mf][j][e];
        }
}

// ---------------- reduce2: out = out + sum parts + bias(p . bw), grid-stride x2 ----------------
__global__ __launch_bounds__(256) void reduce2_kernel(
    float* __restrict__ out, const float* __restrict__ parts,
    const float* __restrict__ pmat, const float* __restrict__ bw, int np)
{
#pragma unroll
    for (int rep = 0; rep < 2; ++rep) {
        size_t i = (size_t)blockIdx.x * 512 + rep * 256 + threadIdx.x;  // float4 idx, 1M total
        int m   = (int)(i >> 8);
        int col = (int)(i & 255) * 4;
        float4 a = ((const float4*)out)[i];
        for (int p = 0; p < np; ++p) {
            float4 b = ((const float4*)(parts + (size_t)p * M_TOK * DDIM))[i];
            a.x += b.x; a.y += b.y; a.z += b.z; a.w += b.w;
        }
        float4 pa = *(const float4*)(pmat + (size_t)m * 8);
        float4 pb = *(const float4*)(pmat + (size_t)m * 8 + 4);
        float4 bias = *(const float4*)(bw + 8 * DDIM + col);
#pragma unroll
        for (int l = 0; l < 8; ++l) {
            float pl = (l < 4) ? ((const float*)&pa)[l] : ((const float*)&pb)[l - 4];
            float4 bl = *(const float4*)(bw + l * DDIM + col);
            bias.x = fmaf(pl, bl.x, bias.x); bias.y = fmaf(pl, bl.y, bias.y);
            bias.z = fmaf(pl, bl.z, bias.z); bias.w = fmaf(pl, bl.w, bias.w);
        }
        a.x += bias.x; a.y += bias.y; a.z += bias.z; a.w += bias.w;
        ((float4*)out)[i] = a;
    }
}

// ================= fallback (round-3 proven): tree_gemm3 + reduce =================
__global__ __launch_bounds__(256, 4) void tree_gemm3(
    const unsigned short* __restrict__ xs, const unsigned short* __restrict__ wp,
    const float* __restrict__ bw, const float* __restrict__ pmat,
    float* __restrict__ out, float* __restrict__ parts, int KG)
{
    __shared__ __align__(16) unsigned short Asm[2][128 * 32];
    __shared__ __align__(16) unsigned short Bsm[2][128 * 32];
    const int tid  = threadIdx.x;
    const int lane = tid & 63;
    const int w    = tid >> 6;
    const int wm   = w >> 1, wn = w & 1;
    const int bx   = blockIdx.x;
    const int xcd  = bx & 7;
    const int ii   = bx >> 3;
    const int mt   = xcd * 4 + (ii >> 3);
    const int nt   = ii & 7;
    const int m0   = mt * 128, n0 = nt * 128;
    const int g    = blockIdx.y;
    const int k0   = g * KG;
    const int ra   = lane & 15;
    const int kb   = (lane >> 4) * 8;
    f32x4 acc[4][4] = {};
    auto stage = [&](int buf, int t) {
#pragma unroll
        for (int c = 0; c < 2; ++c) {
            int row = w * 32 + c * 16 + (lane >> 2);
            int ke  = k0 + t * 32 + (lane & 3) * 8;
            const unsigned short* ga = xs + (size_t)(m0 + row) * KFLAT + ke;
            __builtin_amdgcn_global_load_lds(GLB(ga), LDS(&Asm[buf][w * 1024 + c * 512]), 16, 0, 0);
            const unsigned short* gb = wp + (size_t)(n0 + row) * KFLAT + ke;
            __builtin_amdgcn_global_load_lds(GLB(gb), LDS(&Bsm[buf][w * 1024 + c * 512]), 16, 0, 0);
        }
    };
    const int TOT = KG >> 5;
    stage(0, 0);
    __syncthreads();
    int cur = 0;
    for (int t = 0; t < TOT; ++t) {
        if (t + 1 < TOT) stage(cur ^ 1, t + 1);
        bf16x8 av2[4], bv2[4];
#pragma unroll
        for (int i2 = 0; i2 < 4; ++i2)
            av2[i2] = *(const bf16x8*)&Asm[cur][(wm * 64 + i2 * 16 + ra) * 32 + kb];
#pragma unroll
        for (int j = 0; j < 4; ++j)
            bv2[j] = *(const bf16x8*)&Bsm[cur][(wn * 64 + j * 16 + ra) * 32 + kb];
#pragma unroll
        for (int i2 = 0; i2 < 4; ++i2)
#pragma unroll
            for (int j = 0; j < 4; ++j)
                acc[i2][j] = __builtin_amdgcn_mfma_f32_16x16x32_bf16(av2[i2], bv2[j], acc[i2][j], 0, 0, 0);
        __syncthreads();
        cur ^= 1;
    }
    float* bsm = (float*)&Asm[0][0];
    if (g == 0) {
        for (int idx = tid; idx < 9 * 128; idx += 256)
            bsm[idx] = bw[(idx >> 7) * DDIM + n0 + (idx & 127)];
    }
    __syncthreads();
    float* dst = (g == 0) ? out : parts + (size_t)(g - 1) * M_TOK * DDIM;
#pragma unroll
    for (int i2 = 0; i2 < 4; ++i2)
#pragma unroll
        for (int r = 0; r < 4; ++r) {
            int row = m0 + wm * 64 + i2 * 16 + (lane >> 4) * 4 + r;
            float4 pa, pb;
            if (g == 0) {
                pa = *(const float4*)(pmat + (size_t)row * 8);
                pb = *(const float4*)(pmat + (size_t)row * 8 + 4);
            }
#pragma unroll
            for (int j = 0; j < 4; ++j) {
                int cl = wn * 64 + j * 16 + ra;
                float v = acc[i2][j][r];
                if (g == 0) {
                    v += pa.x * bsm[0 * 128 + cl] + pa.y * bsm[1 * 128 + cl]
                       + pa.z * bsm[2 * 128 + cl] + pa.w * bsm[3 * 128 + cl]
                       + pb.x * bsm[4 * 128 + cl] + pb.y * bsm[5 * 128 + cl]
                       + pb.z * bsm[6 * 128 + cl] + pb.w * bsm[7 * 128 + cl]
                       + bsm[8 * 128 + cl];
                }
                dst[(size_t)row * DDIM + n0 + cl] = v;
            }
        }
}

__global__ __launch_bounds__(256) void reduce_kernel(
    float* __restrict__ out, const float* __restrict__ parts, int np)
{
    size_t i = (size_t)blockIdx.x * 256 + threadIdx.x;
    float4 a = ((const float4*)out)[i];
    for (int p = 0; p < np; ++p) {
        float4 b = ((const float4*)(parts + (size_t)p * M_TOK * DDIM))[i];
        a.x += b.x; a.y += b.y; a.z += b.z; a.w += b.w;
    }
    ((float4*)out)[i] = a;
}

extern "C" void kernel_launch(void* const* d_in, const int* in_sizes, int n_in,
                              void* d_out, int out_size, void* d_ws, size_t ws_size,
                              hipStream_t stream) {
    (void)in_sizes; (void)n_in; (void)out_size;
    const float* x     = (const float*)d_in[0];
    const float* dec_w = (const float*)d_in[1];
    const float* dec_b = (const float*)d_in[2];
    const float* lw    = (const float*)d_in[3];
    const float* lb    = (const float*)d_in[4];
    float* out = (float*)d_out;
    uint8_t* w8 = (uint8_t*)d_ws;

    unsigned short* xs   = (unsigned short*)(w8);
    unsigned short* wp   = (unsigned short*)(w8 + 75497472);
    float*          bw   = (float*)(w8 + 94371840);
    float*          pmat = (float*)(w8 + 94408704);
    float*          parts= (float*)(w8 + 94539776);
    const size_t NEED3 = 94539776 + 2ull * 16777216;
    const size_t NEED4 = 94539776 + 3ull * 16777216;

    int ks = (ws_size >= NEED4) ? 4 : (ws_size >= NEED3) ? 3 : 0;
    if (!ks) return;

    prep_dec_kernel<<<2048, 256, 0, stream>>>(x, dec_w, dec_b, lw, lb, wp, bw, xs, pmat);

    hipError_t e8 = hipFuncSetAttribute(
        reinterpret_cast<const void*>(tree_gemm8),
        hipFuncAttributeMaxDynamicSharedMemorySize, 163840);
    if (e8 == hipSuccess) {
        tree_gemm8<<<dim3(64, ks), 512, 163840, stream>>>(xs, wp, out, parts, KFLAT / ks);
        reduce2_kernel<<<2048, 256, 0, stream>>>(out, parts, pmat, bw, ks - 1);
    } else {
        tree_gemm3<<<dim3(256, ks), 256, 0, stream>>>(xs, wp, bw, pmat, out, parts, KFLAT / ks);
        reduce_kernel<<<4096, 256, 0, stream>>>(out, parts, ks - 1);
    }
}